// Round 7
// baseline (1386.374 us; speedup 1.0000x reference)
//
#include <hip/hip_runtime.h>
#include <hip/hip_bf16.h>

// ---------------------------------------------------------------------------
// TAGConv (K=2) x2 + segment-max pool + linear head. bf16 intermediates,
// fp32 accumulate, int8 row-quantized gathers for ALL props (per-row scale
// folded into norm). Layer-2 commuted: z2@W2 = X1@W2a + P(X1@W2b + P(X1@W2c)).
// Round 7: (a) non-temporal src/dst loads in hist/fill so streaming reads
// don't evict the dirty colidx/deg window from the owning XCD's L2 (r6: 173MB
// writeback for a 12.8MB colidx = LRU eviction churn); (b) layer-1 props go
// int8 too (128B/row instead of 256B), Q8 aliases dead B2.
// ---------------------------------------------------------------------------

typedef unsigned short u16;
typedef unsigned int u32;

__device__ inline float u2f(u16 u) { return __uint_as_float(((u32)u) << 16); }
__device__ inline u16 f2u(float f) {
    __hip_bfloat16 b = __float2bfloat16(f);
    return *reinterpret_cast<u16*>(&b);
}

// ---------------------------- CSR build ------------------------------------
// hist/fill: 8 dst-windows; group w = blockIdx&7 owns window w and scans the
// whole edge list (grid-stride, nt loads). Ownership => one XCD dirties a
// window; nt streaming => dirty lines stay resident until final writeback.

__global__ __launch_bounds__(256) void hist_kernel(
    const int* __restrict__ dst, int* __restrict__ deg, int E, int wstep) {
    int grp = blockIdx.x & 7;
    int vb  = blockIdx.x >> 3;
    int nvb = gridDim.x >> 3;
    int lo = grp * wstep, hi = lo + wstep;
    int stride = nvb * 256;
    for (int i = vb * 256 + threadIdx.x; i < E; i += stride) {
        int d = __builtin_nontemporal_load(dst + i);
        if (d >= lo && d < hi) atomicAdd(&deg[d], 1);
    }
}

__global__ __launch_bounds__(256) void fill_kernel(
    const int* __restrict__ src, const int* __restrict__ dst,
    int* __restrict__ cursor, int* __restrict__ colidx, int E, int wstep) {
    int grp = blockIdx.x & 7;
    int vb  = blockIdx.x >> 3;
    int nvb = gridDim.x >> 3;
    int lo = grp * wstep, hi = lo + wstep;
    int stride = nvb * 256;
    for (int i = vb * 256 + threadIdx.x; i < E; i += stride) {
        int d = __builtin_nontemporal_load(dst + i);
        if (d >= lo && d < hi) {
            int s = __builtin_nontemporal_load(src + i);
            int pos = atomicAdd(&cursor[d], 1);
            colidx[pos] = s;
        }
    }
}

__global__ void norm_kernel(const int* __restrict__ deg, float* __restrict__ normv, int N) {
    int i = blockIdx.x * blockDim.x + threadIdx.x;
    if (i < N) {
        int d = deg[i];
        float fd = d < 1 ? 1.0f : (float)d;
        normv[i] = rsqrtf(fd);
    }
}

// Multi-block scan: scan1 (per-1024-chunk local excl scan + block sums),
// scan2 (single block excl scan of sums), scan3 (add offsets, write cursor).
__global__ void scan1_kernel(const int* __restrict__ deg, int* __restrict__ rowptr,
                             int* __restrict__ bsum, int n) {
    __shared__ int sd[1024];
    int t = threadIdx.x;
    int i = blockIdx.x * 1024 + t;
    int v = (i < n) ? deg[i] : 0;
    sd[t] = v;
    __syncthreads();
    for (int off = 1; off < 1024; off <<= 1) {
        int x = (t >= off) ? sd[t - off] : 0;
        __syncthreads();
        sd[t] += x;
        __syncthreads();
    }
    if (i < n) rowptr[i] = sd[t] - v;
    if (t == 1023) bsum[blockIdx.x] = sd[t];
}

__global__ void scan2_kernel(int* __restrict__ bsum, int nb) {
    __shared__ int sd[1024];
    int t = threadIdx.x;
    int v = (t < nb) ? bsum[t] : 0;
    sd[t] = v;
    __syncthreads();
    for (int off = 1; off < 1024; off <<= 1) {
        int x = (t >= off) ? sd[t - off] : 0;
        __syncthreads();
        sd[t] += x;
        __syncthreads();
    }
    if (t < nb) bsum[t] = sd[t] - v;
}

__global__ void scan3_kernel(int* __restrict__ rowptr, int* __restrict__ cursor,
                             const int* __restrict__ bsum, int n, int E) {
    int i = blockIdx.x * blockDim.x + threadIdx.x;
    if (i < n) {
        int r = rowptr[i] + bsum[i >> 10];
        rowptr[i] = r;
        cursor[i] = r;
    }
    if (i == 0) rowptr[n] = E;
}

// ------------------------------ cast h -------------------------------------

struct alignas(4) U2 { u16 v[2]; };
struct alignas(8) U4 { u16 v[4]; };

// CAT1[:, 0:IN] = bf16(h), 4 floats per thread
__global__ void cast_kernel(const float* __restrict__ h, u16* __restrict__ cat,
                            int ngroups, int in4, int ldcat) {
    int i = blockIdx.x * blockDim.x + threadIdx.x;
    if (i < ngroups) {
        int r = i / in4, c4 = i % in4;
        float4 f = *(const float4*)(h + (size_t)i * 4);
        U4 o;
        o.v[0] = f2u(f.x); o.v[1] = f2u(f.y); o.v[2] = f2u(f.z); o.v[3] = f2u(f.w);
        *(U4*)(cat + (size_t)r * ldcat + c4 * 4) = o;
    }
}

// --------------------------- int8 quantization -----------------------------
// q[i,:] = round(x[i,:] * 127/rowmax), m[i] = norm[i] * rowmax/127.

// d=128, from fp32 (h). Lane holds 2 features.
__global__ __launch_bounds__(256) void quant_f32_128(
    const float* __restrict__ x, const float* __restrict__ normv,
    signed char* __restrict__ q, float* __restrict__ m, int N) {
    int row = blockIdx.x * 4 + (threadIdx.x >> 6);
    if (row >= N) return;
    int lane = threadIdx.x & 63;
    float2 f = *(const float2*)(x + (size_t)row * 128 + lane * 2);
    float mx = fmaxf(fabsf(f.x), fabsf(f.y));
    #pragma unroll
    for (int off = 32; off > 0; off >>= 1)
        mx = fmaxf(mx, __shfl_xor(mx, off, 64));
    float inv = mx > 0.f ? 127.f / mx : 0.f;
    char2 o;
    o.x = (signed char)(int)rintf(f.x * inv);
    o.y = (signed char)(int)rintf(f.y * inv);
    *(char2*)(q + (size_t)row * 128 + lane * 2) = o;
    if (lane == 0) m[row] = normv[row] * (mx * (1.f / 127.f));
}

// d=128, from bf16 with row stride ldx. Lane holds 2 features.
__global__ __launch_bounds__(256) void quant_bf16_128(
    const u16* __restrict__ x, int ldx, const float* __restrict__ normv,
    signed char* __restrict__ q, float* __restrict__ m, int N) {
    int row = blockIdx.x * 4 + (threadIdx.x >> 6);
    if (row >= N) return;
    int lane = threadIdx.x & 63;
    U2 v = *(const U2*)(x + (size_t)row * ldx + lane * 2);
    float f0 = u2f(v.v[0]), f1 = u2f(v.v[1]);
    float mx = fmaxf(fabsf(f0), fabsf(f1));
    #pragma unroll
    for (int off = 32; off > 0; off >>= 1)
        mx = fmaxf(mx, __shfl_xor(mx, off, 64));
    float inv = mx > 0.f ? 127.f / mx : 0.f;
    char2 o;
    o.x = (signed char)(int)rintf(f0 * inv);
    o.y = (signed char)(int)rintf(f1 * inv);
    *(char2*)(q + (size_t)row * 128 + lane * 2) = o;
    if (lane == 0) m[row] = normv[row] * (mx * (1.f / 127.f));
}

// d=256, from bf16 (ld=256). Lane holds 4 features.
__global__ __launch_bounds__(256) void quant_bf16_256(
    const u16* __restrict__ x, const float* __restrict__ normv,
    signed char* __restrict__ q, float* __restrict__ m, int N) {
    int row = blockIdx.x * 4 + (threadIdx.x >> 6);
    if (row >= N) return;
    int lane = threadIdx.x & 63;
    U4 v = *(const U4*)(x + (size_t)row * 256 + lane * 4);
    float f[4];
    #pragma unroll
    for (int i = 0; i < 4; ++i) f[i] = u2f(v.v[i]);
    float mx = fmaxf(fmaxf(fabsf(f[0]), fabsf(f[1])),
                     fmaxf(fabsf(f[2]), fabsf(f[3])));
    #pragma unroll
    for (int off = 32; off > 0; off >>= 1)
        mx = fmaxf(mx, __shfl_xor(mx, off, 64));
    float inv = mx > 0.f ? 127.f / mx : 0.f;
    char4 o;
    o.x = (signed char)(int)rintf(f[0] * inv);
    o.y = (signed char)(int)rintf(f[1] * inv);
    o.z = (signed char)(int)rintf(f[2] * inv);
    o.w = (signed char)(int)rintf(f[3] * inv);
    *(char4*)(q + (size_t)row * 256 + lane * 4) = o;
    if (lane == 0) m[row] = normv[row] * (mx * (1.f / 127.f));
}

// ------------------------- int8 row-quantized prop -------------------------
// out[i,:] = norm[i] * sum_e m[col_e] * q[col_e,:]  -> bf16 (stride ldout).
// FPL = features per lane (4 => d=256 int loads, 2 => d=128 ushort loads).
// One wave per node, edge loop unrolled x8.

template <int FPL>
__global__ __launch_bounds__(256) void prop_q8_kernel(
    const signed char* __restrict__ qin, const float* __restrict__ m,
    u16* __restrict__ out, int ldout,
    const int* __restrict__ rowptr, const int* __restrict__ colidx,
    const float* __restrict__ normv, int N) {
    const int D = 64 * FPL;
    int node = blockIdx.x * 4 + (threadIdx.x >> 6);
    if (node >= N) return;
    int lane = threadIdx.x & 63;
    const signed char* ip = qin + lane * FPL;
    int s = rowptr[node], e = rowptr[node + 1];
    float acc[FPL];
    #pragma unroll
    for (int q = 0; q < FPL; ++q) acc[q] = 0.f;
    int p = s;
    for (; p + 8 <= e; p += 8) {
        int c[8];
        #pragma unroll
        for (int j = 0; j < 8; ++j) c[j] = colidx[p + j];
        int w[8];
        #pragma unroll
        for (int j = 0; j < 8; ++j) {
            if (FPL == 4) w[j] = *(const int*)(ip + (size_t)c[j] * D);
            else          w[j] = *(const unsigned short*)(ip + (size_t)c[j] * D);
        }
        float nm[8];
        #pragma unroll
        for (int j = 0; j < 8; ++j) nm[j] = m[c[j]];
        #pragma unroll
        for (int j = 0; j < 8; ++j) {
            acc[0] += nm[j] * (float)(signed char)(w[j]);
            acc[1] += nm[j] * (float)(signed char)(w[j] >> 8);
            if (FPL == 4) {
                acc[2] += nm[j] * (float)(signed char)(w[j] >> 16);
                acc[3] += nm[j] * (float)(w[j] >> 24);
            }
        }
    }
    for (; p < e; ++p) {
        int c = colidx[p];
        int w;
        if (FPL == 4) w = *(const int*)(ip + (size_t)c * D);
        else          w = *(const unsigned short*)(ip + (size_t)c * D);
        float nm = m[c];
        acc[0] += nm * (float)(signed char)(w);
        acc[1] += nm * (float)(signed char)(w >> 8);
        if (FPL == 4) {
            acc[2] += nm * (float)(signed char)(w >> 16);
            acc[3] += nm * (float)(w >> 24);
        }
    }
    float nn = normv[node];
    if (FPL == 4) {
        U4 o;
        #pragma unroll
        for (int q = 0; q < 4; ++q) o.v[q] = f2u(nn * acc[q]);
        *(U4*)(out + (size_t)node * ldout + lane * 4) = o;
    } else {
        U2 o;
        o.v[0] = f2u(nn * acc[0]);
        o.v[1] = f2u(nn * acc[1]);
        *(U2*)(out + (size_t)node * ldout + lane * 2) = o;
    }
}

// ------------------------------- MFMA GEMM ---------------------------------
// Cout[M x 256] = [relu]( A(bf16,[Mpad x lda]) @ Bt^T [+Cadd] [+bias] ) -> bf16
// Bt is [256 x K] bf16 row-major (pre-transposed weights, k-contiguous).
// Tile 128x64, BK=32, 4 waves (2x2), wave = 4x2 grid of 16x16x32 MFMAs.
// B panel LDS-resident; A tile double-buffered via global_load_lds width-16.

typedef __attribute__((ext_vector_type(8))) short bf16x8f;
typedef __attribute__((ext_vector_type(4))) float f32x4;

__device__ inline void async16(const void* g, void* l) {
    __builtin_amdgcn_global_load_lds(
        (__attribute__((address_space(1))) void*)(g),
        (__attribute__((address_space(3))) void*)(l), 16, 0, 0);
}

constexpr int GBM = 128, GBN = 64, GBK = 32, KMAX = 384;

__device__ inline void stageA(const u16* __restrict__ A, int lda, int row0, int k0,
                              u16* dst, int tid) {
    // 128 rows x 32 bf16 cols = 8 KB = 512 x 16B chunks; 256 threads x 2.
    #pragma unroll
    for (int i = 0; i < 2; ++i) {
        int c = tid + i * 256;
        int row = c >> 2, seg = c & 3;
        async16(A + (size_t)(row0 + row) * lda + k0 + seg * 8, dst + c * 8);
    }
}

__global__ __launch_bounds__(256) void gemm_mfma(
    const u16* __restrict__ A, int lda,
    const u16* __restrict__ Bt,          // [256 x K]
    const u16* __restrict__ Cadd,        // nullable, [Mpad x 256]
    const float* __restrict__ bias,      // nullable, [256]
    u16* __restrict__ Cout,              // [Mpad x 256]
    int M, int K, int relu) {
    __shared__ u16 Ab[2][GBM * GBK];
    __shared__ u16 Bs[GBN * KMAX];
    const int tid = threadIdx.x;
    const int lane = tid & 63;
    const int wave = tid >> 6;
    const int wm = wave >> 1, wn = wave & 1;
    const int row0 = blockIdx.x * GBM;
    const int col0 = blockIdx.y * GBN;
    const int NOUT = 256;

    // stage B panel: contiguous 64*K bf16 from Bt + col0*K
    {
        const u16* src = Bt + (size_t)col0 * K;
        int chunks = GBN * K / 8;
        for (int c = tid; c < chunks; c += 256) async16(src + c * 8, &Bs[c * 8]);
    }
    stageA(A, lda, row0, 0, Ab[0], tid);
    __syncthreads();

    f32x4 acc[4][2];
    #pragma unroll
    for (int mi = 0; mi < 4; ++mi)
        #pragma unroll
        for (int ni = 0; ni < 2; ++ni) acc[mi][ni] = (f32x4)0.f;

    const int nk = K / GBK;
    const int mb = lane & 15;
    const int kk = (lane >> 4) * 8;
    for (int ks = 0; ks < nk; ++ks) {
        int cur = ks & 1;
        if (ks + 1 < nk) stageA(A, lda, row0, (ks + 1) * GBK, Ab[cur ^ 1], tid);
        bf16x8f a[4], b[2];
        #pragma unroll
        for (int mi = 0; mi < 4; ++mi)
            a[mi] = *(const bf16x8f*)&Ab[cur][(wm * 64 + mi * 16 + mb) * GBK + kk];
        #pragma unroll
        for (int ni = 0; ni < 2; ++ni)
            b[ni] = *(const bf16x8f*)&Bs[(size_t)(wn * 32 + ni * 16 + mb) * K + ks * GBK + kk];
        #pragma unroll
        for (int mi = 0; mi < 4; ++mi)
            #pragma unroll
            for (int ni = 0; ni < 2; ++ni)
                acc[mi][ni] = __builtin_amdgcn_mfma_f32_16x16x32_bf16(
                    a[mi], b[ni], acc[mi][ni], 0, 0, 0);
        __syncthreads();
    }

    // epilogue: C/D layout col = lane&15, row = (lane>>4)*4 + r
    #pragma unroll
    for (int mi = 0; mi < 4; ++mi) {
        #pragma unroll
        for (int r = 0; r < 4; ++r) {
            int row = row0 + wm * 64 + mi * 16 + (lane >> 4) * 4 + r;
            if (row < M) {
                #pragma unroll
                for (int ni = 0; ni < 2; ++ni) {
                    int col = col0 + wn * 32 + ni * 16 + (lane & 15);
                    float v = acc[mi][ni][r];
                    if (Cadd) v += u2f(Cadd[(size_t)row * NOUT + col]);
                    if (bias) v += bias[col];
                    if (relu) v = fmaxf(v, 0.f);
                    Cout[(size_t)row * NOUT + col] = f2u(v);
                }
            }
        }
    }
}

// Wt[n*K + k] = bf16(W[k*Nn + n])
__global__ void transpose_cast(const float* __restrict__ W, u16* __restrict__ Wt,
                               int K, int Nn) {
    int idx = blockIdx.x * blockDim.x + threadIdx.x;
    if (idx < K * Nn) {
        int n = idx / K, k = idx % K;
        Wt[idx] = f2u(W[(size_t)k * Nn + n]);
    }
}

// ------------------------------ pool + head --------------------------------

__global__ void pool_kernel(const u16* __restrict__ x, const int* __restrict__ gid,
                            float* __restrict__ pooled, int N, int HID) {
    int t = threadIdx.x;
    int n0 = blockIdx.x * 128;
    int n1 = n0 + 128 < N ? n0 + 128 : N;
    float cur = 0.f;
    int cg = gid[n0];
    for (int n = n0; n < n1; ++n) {
        int g = gid[n];
        if (g != cg) {
            atomicMax((int*)&pooled[(size_t)cg * HID + t], __float_as_int(cur));
            cg = g;
            cur = 0.f;
        }
        float v = u2f(x[(size_t)n * HID + t]);
        cur = cur > v ? cur : v;
    }
    atomicMax((int*)&pooled[(size_t)cg * HID + t], __float_as_int(cur));
}

__global__ void head_kernel(const float* __restrict__ pooled, const float* __restrict__ Wc,
                            const float* __restrict__ bc, float* __restrict__ out,
                            int HID, int C) {
    __shared__ float row[256];
    int g = blockIdx.x;
    int t = threadIdx.x;
    if (t < HID) row[t] = pooled[(size_t)g * HID + t];
    __syncthreads();
    if (t < C) {
        float s = bc[t];
        for (int k = 0; k < HID; ++k) s += row[k] * Wc[(size_t)k * C + t];
        out[(size_t)g * C + t] = s;
    }
}

// ------------------------------- launch ------------------------------------

extern "C" void kernel_launch(void* const* d_in, const int* in_sizes, int n_in,
                              void* d_out, int out_size, void* d_ws, size_t ws_size,
                              hipStream_t stream) {
    const float* h  = (const float*)d_in[0];
    const int* src  = (const int*)d_in[1];
    const int* dst  = (const int*)d_in[2];
    const int* gid  = (const int*)d_in[3];
    const float* W1 = (const float*)d_in[4];
    const float* b1 = (const float*)d_in[5];
    const float* W2 = (const float*)d_in[6];
    const float* b2 = (const float*)d_in[7];
    const float* Wc = (const float*)d_in[8];
    const float* bc = (const float*)d_in[9];
    float* out = (float*)d_out;

    const int N   = in_sizes[3];          // 100000
    const int E   = in_sizes[1];          // 3200000
    const int IN  = in_sizes[0] / N;      // 128
    const int HID = in_sizes[5];          // 256
    const int C   = in_sizes[9];          // 10
    const int G   = out_size / C;         // 64
    const int CAT = 3 * IN;               // 384
    const int Mpad = (N + 127) & ~127;    // 100096 (multiple of GBM)

    char* wp = (char*)d_ws;
    auto alloc = [&](size_t bytes) {
        char* p = wp;
        wp += (bytes + 255) & ~(size_t)255;
        return p;
    };
    float* pooled = (float*)alloc((size_t)G * HID * sizeof(float));
    float* normv  = (float*)alloc((size_t)N * sizeof(float));
    int* deg      = (int*)alloc((size_t)N * sizeof(int));
    int* rowptr   = (int*)alloc((size_t)(N + 1) * sizeof(int));
    int* cursor   = (int*)alloc((size_t)N * sizeof(int));
    int* bsum     = (int*)alloc(1024 * sizeof(int));
    int* colidx   = (int*)alloc((size_t)E * sizeof(int));
    u16* Wt1      = (u16*)alloc((size_t)CAT * HID * sizeof(u16));        // [256 x 384]
    u16* Wt2      = (u16*)alloc((size_t)3 * HID * HID * sizeof(u16));    // 3 x [256 x 256]
    u16* CAT1     = (u16*)alloc((size_t)Mpad * CAT * sizeof(u16));       // [h|Ph|P2h]
    u16* X1       = (u16*)alloc((size_t)Mpad * HID * sizeof(u16));
    u16* B2       = (u16*)alloc((size_t)Mpad * HID * sizeof(u16));
    u16* B1       = CAT1;                              // alias: CAT1 dead after GEMM1
    signed char* Q8L2 = (signed char*)(CAT1 + (size_t)Mpad * HID);  // CAT1 tail, layer-2
    signed char* Q8L1 = (signed char*)B2;              // B2 dead during layer 1
    float* mv     = (float*)cursor;                    // cursor dead after fill

    // --- norm + CSR build (8 ownership windows over dst, nt streaming) ---
    const int wstep = (N + 7) / 8;        // 12500
    hipMemsetAsync(deg, 0, (size_t)N * sizeof(int), stream);
    hist_kernel<<<8 * 512, 256, 0, stream>>>(dst, deg, E, wstep);
    norm_kernel<<<(N + 255) / 256, 256, 0, stream>>>(deg, normv, N);
    int nb = (N + 1023) / 1024;
    scan1_kernel<<<nb, 1024, 0, stream>>>(deg, rowptr, bsum, N);
    scan2_kernel<<<1, 1024, 0, stream>>>(bsum, nb);
    scan3_kernel<<<(N + 255) / 256, 256, 0, stream>>>(rowptr, cursor, bsum, N, E);
    fill_kernel<<<8 * 512, 256, 0, stream>>>(src, dst, cursor, colidx, E, wstep);

    // --- weight transpose + bf16 cast (small) ---
    transpose_cast<<<(CAT * HID + 255) / 256, 256, 0, stream>>>(W1, Wt1, CAT, HID);
    for (int s2 = 0; s2 < 3; ++s2)
        transpose_cast<<<(HID * HID + 255) / 256, 256, 0, stream>>>(
            W2 + (size_t)s2 * HID * HID, Wt2 + (size_t)s2 * HID * HID, HID, HID);

    // --- layer 1: CAT1 = [bf16(h) | P h | P^2 h]; X1 = relu(CAT1@W1+b1) ---
    {
        int ngroups = N * (IN / 4);
        cast_kernel<<<(ngroups + 255) / 256, 256, 0, stream>>>(h, CAT1, ngroups, IN / 4, CAT);
    }
    int pb = (N + 3) / 4;
    quant_f32_128<<<pb, 256, 0, stream>>>(h, normv, Q8L1, mv, N);
    prop_q8_kernel<2><<<pb, 256, 0, stream>>>(Q8L1, mv, CAT1 + IN, CAT,
                                              rowptr, colidx, normv, N);
    quant_bf16_128<<<pb, 256, 0, stream>>>(CAT1 + IN, CAT, normv, Q8L1, mv, N);
    prop_q8_kernel<2><<<pb, 256, 0, stream>>>(Q8L1, mv, CAT1 + 2 * IN, CAT,
                                              rowptr, colidx, normv, N);
    dim3 ggrid(Mpad / GBM, HID / GBN);
    gemm_mfma<<<ggrid, 256, 0, stream>>>(CAT1, CAT, Wt1, nullptr, b1, X1, N, CAT, 1);

    // --- layer 2 (commuted): X2 = relu(X1@W2a + P(X1@W2b + P(X1@W2c)) + b2) ---
    gemm_mfma<<<ggrid, 256, 0, stream>>>(X1, HID, Wt2 + (size_t)2 * HID * HID,
                                         nullptr, nullptr, B1, N, HID, 0);
    quant_bf16_256<<<pb, 256, 0, stream>>>(B1, normv, Q8L2, mv, N);
    prop_q8_kernel<4><<<pb, 256, 0, stream>>>(Q8L2, mv, B2, HID,
                                              rowptr, colidx, normv, N);
    gemm_mfma<<<ggrid, 256, 0, stream>>>(X1, HID, Wt2 + (size_t)HID * HID,
                                         B2, nullptr, B1, N, HID, 0);
    quant_bf16_256<<<pb, 256, 0, stream>>>(B1, normv, Q8L2, mv, N);
    prop_q8_kernel<4><<<pb, 256, 0, stream>>>(Q8L2, mv, B2, HID,
                                              rowptr, colidx, normv, N);
    gemm_mfma<<<ggrid, 256, 0, stream>>>(X1, HID, Wt2, B2, b2, B1, N, HID, 1);

    // --- pool + head ---
    hipMemsetAsync(pooled, 0, (size_t)G * HID * sizeof(float), stream);
    pool_kernel<<<(N + 127) / 128, HID, 0, stream>>>(B1, gid, pooled, N, HID);
    head_kernel<<<G, HID, 0, stream>>>(pooled, Wc, bc, out, HID, C);
}

// Round 8
// 1242.632 us; speedup vs baseline: 1.1157x; 1.1157x over previous
//
#include <hip/hip_runtime.h>
#include <hip/hip_bf16.h>

// ---------------------------------------------------------------------------
// TAGConv (K=2) x2 + segment-max pool + linear head. bf16 intermediates,
// fp32 accumulate, int8 row-quantized gathers for ALL props (per-row scale
// folded into norm). Layer-2 commuted: z2@W2 = X1@W2a + P(X1@W2b + P(X1@W2c)).
// Round 8: atomic-free CSR build via two-level counting sort (r7 evidence:
// fill at 23G atomics/s, 1.7TB/s, VALU 5% = global-atomic throughput wall).
//   A: per-chunk LDS histogram over 782 dst-buckets -> Hmat[b][c]
//   B: exclusive scan of Hmat (bucket-major)
//   C: chunk scatter into bucket-grouped Earr, LDS cursors only
//   D: per-bucket fine count/scan -> rowptr+normv+colidx, cluster-local writes
// ---------------------------------------------------------------------------

typedef unsigned short u16;
typedef unsigned int u32;

__device__ inline float u2f(u16 u) { return __uint_as_float(((u32)u) << 16); }
__device__ inline u16 f2u(float f) {
    __hip_bfloat16 b = __float2bfloat16(f);
    return *reinterpret_cast<u16*>(&b);
}

// ---------------------- CSR build: counting sort ---------------------------
// NPB = 128 nodes per bucket, NC = 128 edge chunks. NB = ceil(N/NPB) <= 784.

constexpr int NPB = 128, NC = 128, NBMAX = 784;

__global__ __launch_bounds__(256) void countA_kernel(
    const int* __restrict__ dst, int* __restrict__ Hmat, int E, int CS, int NB) {
    __shared__ int hist[NBMAX];
    int tid = threadIdx.x;
    for (int b = tid; b < NB; b += 256) hist[b] = 0;
    __syncthreads();
    int base = blockIdx.x * CS;
    int end = base + CS < E ? base + CS : E;
    for (int i = base + tid; i < end; i += 256) {
        int d = __builtin_nontemporal_load(dst + i);
        atomicAdd(&hist[d >> 7], 1);
    }
    __syncthreads();
    for (int b = tid; b < NB; b += 256) Hmat[b * NC + blockIdx.x] = hist[b];
}

__global__ __launch_bounds__(256) void scatterC_kernel(
    const int* __restrict__ src, const int* __restrict__ dst,
    const int* __restrict__ Omat, uint2* __restrict__ Earr,
    int E, int CS, int NB) {
    __shared__ int cur[NBMAX];
    int tid = threadIdx.x;
    int c = blockIdx.x;
    for (int b = tid; b < NB; b += 256) cur[b] = Omat[b * NC + c];
    __syncthreads();
    int base = c * CS;
    int end = base + CS < E ? base + CS : E;
    for (int i = base + tid; i < end; i += 256) {
        int d = __builtin_nontemporal_load(dst + i);
        int s = __builtin_nontemporal_load(src + i);
        int pos = atomicAdd(&cur[d >> 7], 1);
        uint2 e;
        e.x = (u32)s;
        e.y = (u32)(d & (NPB - 1));
        Earr[pos] = e;
    }
}

// One block per bucket: local deg count -> rowptr/normv, then colidx scatter.
__global__ __launch_bounds__(256) void fineD_kernel(
    const uint2* __restrict__ Earr, const int* __restrict__ Omat,
    int* __restrict__ colidx, int* __restrict__ rowptr,
    float* __restrict__ normv, int N, int E, int NB) {
    __shared__ int cnt[NPB];
    __shared__ int scn[NPB];
    __shared__ int cur2[NPB];
    int tid = threadIdx.x;
    int b = blockIdx.x;
    int base = Omat[b * NC];
    int end = Omat[(b + 1) * NC];   // Omat[NB*NC] = E (scan tail)
    if (tid < NPB) cnt[tid] = 0;
    __syncthreads();
    for (int i = base + tid; i < end; i += 256)
        atomicAdd(&cnt[Earr[i].y], 1);
    __syncthreads();
    if (tid < NPB) scn[tid] = cnt[tid];
    __syncthreads();
    for (int off = 1; off < NPB; off <<= 1) {
        int v = (tid < NPB && tid >= off) ? scn[tid - off] : 0;
        __syncthreads();
        if (tid < NPB) scn[tid] += v;
        __syncthreads();
    }
    // scn = inclusive; exclusive = scn - cnt
    int node0 = b * NPB;
    if (tid < NPB) {
        int excl = scn[tid] - cnt[tid];
        cur2[tid] = base + excl;
        int node = node0 + tid;
        if (node < N) {
            rowptr[node] = base + excl;
            int d = cnt[tid];
            float fd = d < 1 ? 1.0f : (float)d;
            normv[node] = rsqrtf(fd);
        }
    }
    if (b == 0 && tid == 0) rowptr[N] = E;
    __syncthreads();
    for (int i = base + tid; i < end; i += 256) {
        uint2 e = Earr[i];
        int pos = atomicAdd(&cur2[e.y], 1);
        colidx[pos] = (int)e.x;
    }
}

// Multi-block scan: scan1 (per-1024-chunk local excl scan + block sums),
// scan2 (single block excl scan of sums), scan3 (add offsets + tail=E).
__global__ void scan1_kernel(const int* __restrict__ in, int* __restrict__ outp,
                             int* __restrict__ bsum, int n) {
    __shared__ int sd[1024];
    int t = threadIdx.x;
    int i = blockIdx.x * 1024 + t;
    int v = (i < n) ? in[i] : 0;
    sd[t] = v;
    __syncthreads();
    for (int off = 1; off < 1024; off <<= 1) {
        int x = (t >= off) ? sd[t - off] : 0;
        __syncthreads();
        sd[t] += x;
        __syncthreads();
    }
    if (i < n) outp[i] = sd[t] - v;
    if (t == 1023) bsum[blockIdx.x] = sd[t];
}

__global__ void scan2_kernel(int* __restrict__ bsum, int nb) {
    __shared__ int sd[1024];
    int t = threadIdx.x;
    int v = (t < nb) ? bsum[t] : 0;
    sd[t] = v;
    __syncthreads();
    for (int off = 1; off < 1024; off <<= 1) {
        int x = (t >= off) ? sd[t - off] : 0;
        __syncthreads();
        sd[t] += x;
        __syncthreads();
    }
    if (t < nb) bsum[t] = sd[t] - v;
}

__global__ void scan3_kernel(int* __restrict__ outp, const int* __restrict__ bsum,
                             int n, int E) {
    int i = blockIdx.x * blockDim.x + threadIdx.x;
    if (i < n) outp[i] += bsum[i >> 10];
    if (i == 0) outp[n] = E;
}

// ------------------------------ cast h -------------------------------------

struct alignas(4) U2 { u16 v[2]; };
struct alignas(8) U4 { u16 v[4]; };

// CAT1[:, 0:IN] = bf16(h), 4 floats per thread
__global__ void cast_kernel(const float* __restrict__ h, u16* __restrict__ cat,
                            int ngroups, int in4, int ldcat) {
    int i = blockIdx.x * blockDim.x + threadIdx.x;
    if (i < ngroups) {
        int r = i / in4, c4 = i % in4;
        float4 f = *(const float4*)(h + (size_t)i * 4);
        U4 o;
        o.v[0] = f2u(f.x); o.v[1] = f2u(f.y); o.v[2] = f2u(f.z); o.v[3] = f2u(f.w);
        *(U4*)(cat + (size_t)r * ldcat + c4 * 4) = o;
    }
}

// --------------------------- int8 quantization -----------------------------
// q[i,:] = round(x[i,:] * 127/rowmax), m[i] = norm[i] * rowmax/127.

__global__ __launch_bounds__(256) void quant_f32_128(
    const float* __restrict__ x, const float* __restrict__ normv,
    signed char* __restrict__ q, float* __restrict__ m, int N) {
    int row = blockIdx.x * 4 + (threadIdx.x >> 6);
    if (row >= N) return;
    int lane = threadIdx.x & 63;
    float2 f = *(const float2*)(x + (size_t)row * 128 + lane * 2);
    float mx = fmaxf(fabsf(f.x), fabsf(f.y));
    #pragma unroll
    for (int off = 32; off > 0; off >>= 1)
        mx = fmaxf(mx, __shfl_xor(mx, off, 64));
    float inv = mx > 0.f ? 127.f / mx : 0.f;
    char2 o;
    o.x = (signed char)(int)rintf(f.x * inv);
    o.y = (signed char)(int)rintf(f.y * inv);
    *(char2*)(q + (size_t)row * 128 + lane * 2) = o;
    if (lane == 0) m[row] = normv[row] * (mx * (1.f / 127.f));
}

__global__ __launch_bounds__(256) void quant_bf16_128(
    const u16* __restrict__ x, int ldx, const float* __restrict__ normv,
    signed char* __restrict__ q, float* __restrict__ m, int N) {
    int row = blockIdx.x * 4 + (threadIdx.x >> 6);
    if (row >= N) return;
    int lane = threadIdx.x & 63;
    U2 v = *(const U2*)(x + (size_t)row * ldx + lane * 2);
    float f0 = u2f(v.v[0]), f1 = u2f(v.v[1]);
    float mx = fmaxf(fabsf(f0), fabsf(f1));
    #pragma unroll
    for (int off = 32; off > 0; off >>= 1)
        mx = fmaxf(mx, __shfl_xor(mx, off, 64));
    float inv = mx > 0.f ? 127.f / mx : 0.f;
    char2 o;
    o.x = (signed char)(int)rintf(f0 * inv);
    o.y = (signed char)(int)rintf(f1 * inv);
    *(char2*)(q + (size_t)row * 128 + lane * 2) = o;
    if (lane == 0) m[row] = normv[row] * (mx * (1.f / 127.f));
}

__global__ __launch_bounds__(256) void quant_bf16_256(
    const u16* __restrict__ x, const float* __restrict__ normv,
    signed char* __restrict__ q, float* __restrict__ m, int N) {
    int row = blockIdx.x * 4 + (threadIdx.x >> 6);
    if (row >= N) return;
    int lane = threadIdx.x & 63;
    U4 v = *(const U4*)(x + (size_t)row * 256 + lane * 4);
    float f[4];
    #pragma unroll
    for (int i = 0; i < 4; ++i) f[i] = u2f(v.v[i]);
    float mx = fmaxf(fmaxf(fabsf(f[0]), fabsf(f[1])),
                     fmaxf(fabsf(f[2]), fabsf(f[3])));
    #pragma unroll
    for (int off = 32; off > 0; off >>= 1)
        mx = fmaxf(mx, __shfl_xor(mx, off, 64));
    float inv = mx > 0.f ? 127.f / mx : 0.f;
    char4 o;
    o.x = (signed char)(int)rintf(f[0] * inv);
    o.y = (signed char)(int)rintf(f[1] * inv);
    o.z = (signed char)(int)rintf(f[2] * inv);
    o.w = (signed char)(int)rintf(f[3] * inv);
    *(char4*)(q + (size_t)row * 256 + lane * 4) = o;
    if (lane == 0) m[row] = normv[row] * (mx * (1.f / 127.f));
}

// ------------------------- int8 row-quantized prop -------------------------
// out[i,:] = norm[i] * sum_e m[col_e] * q[col_e,:]  -> bf16 (stride ldout).
// FPL = features per lane (4 => d=256, 2 => d=128). Edge loop unrolled x8.

template <int FPL>
__global__ __launch_bounds__(256) void prop_q8_kernel(
    const signed char* __restrict__ qin, const float* __restrict__ m,
    u16* __restrict__ out, int ldout,
    const int* __restrict__ rowptr, const int* __restrict__ colidx,
    const float* __restrict__ normv, int N) {
    const int D = 64 * FPL;
    int node = blockIdx.x * 4 + (threadIdx.x >> 6);
    if (node >= N) return;
    int lane = threadIdx.x & 63;
    const signed char* ip = qin + lane * FPL;
    int s = rowptr[node], e = rowptr[node + 1];
    float acc[FPL];
    #pragma unroll
    for (int q = 0; q < FPL; ++q) acc[q] = 0.f;
    int p = s;
    for (; p + 8 <= e; p += 8) {
        int c[8];
        #pragma unroll
        for (int j = 0; j < 8; ++j) c[j] = colidx[p + j];
        int w[8];
        #pragma unroll
        for (int j = 0; j < 8; ++j) {
            if (FPL == 4) w[j] = *(const int*)(ip + (size_t)c[j] * D);
            else          w[j] = *(const unsigned short*)(ip + (size_t)c[j] * D);
        }
        float nm[8];
        #pragma unroll
        for (int j = 0; j < 8; ++j) nm[j] = m[c[j]];
        #pragma unroll
        for (int j = 0; j < 8; ++j) {
            acc[0] += nm[j] * (float)(signed char)(w[j]);
            acc[1] += nm[j] * (float)(signed char)(w[j] >> 8);
            if (FPL == 4) {
                acc[2] += nm[j] * (float)(signed char)(w[j] >> 16);
                acc[3] += nm[j] * (float)(w[j] >> 24);
            }
        }
    }
    for (; p < e; ++p) {
        int c = colidx[p];
        int w;
        if (FPL == 4) w = *(const int*)(ip + (size_t)c * D);
        else          w = *(const unsigned short*)(ip + (size_t)c * D);
        float nm = m[c];
        acc[0] += nm * (float)(signed char)(w);
        acc[1] += nm * (float)(signed char)(w >> 8);
        if (FPL == 4) {
            acc[2] += nm * (float)(signed char)(w >> 16);
            acc[3] += nm * (float)(w >> 24);
        }
    }
    float nn = normv[node];
    if (FPL == 4) {
        U4 o;
        #pragma unroll
        for (int q = 0; q < 4; ++q) o.v[q] = f2u(nn * acc[q]);
        *(U4*)(out + (size_t)node * ldout + lane * 4) = o;
    } else {
        U2 o;
        o.v[0] = f2u(nn * acc[0]);
        o.v[1] = f2u(nn * acc[1]);
        *(U2*)(out + (size_t)node * ldout + lane * 2) = o;
    }
}

// ------------------------------- MFMA GEMM ---------------------------------
// Cout[M x 256] = [relu]( A(bf16,[Mpad x lda]) @ Bt^T [+Cadd] [+bias] ) -> bf16
// Bt is [256 x K] bf16 row-major. Tile 128x64, BK=32, 4 waves (2x2),
// B panel LDS-resident; A tile double-buffered via global_load_lds width-16.

typedef __attribute__((ext_vector_type(8))) short bf16x8f;
typedef __attribute__((ext_vector_type(4))) float f32x4;

__device__ inline void async16(const void* g, void* l) {
    __builtin_amdgcn_global_load_lds(
        (__attribute__((address_space(1))) void*)(g),
        (__attribute__((address_space(3))) void*)(l), 16, 0, 0);
}

constexpr int GBM = 128, GBN = 64, GBK = 32, KMAX = 384;

__device__ inline void stageA(const u16* __restrict__ A, int lda, int row0, int k0,
                              u16* dst, int tid) {
    #pragma unroll
    for (int i = 0; i < 2; ++i) {
        int c = tid + i * 256;
        int row = c >> 2, seg = c & 3;
        async16(A + (size_t)(row0 + row) * lda + k0 + seg * 8, dst + c * 8);
    }
}

__global__ __launch_bounds__(256) void gemm_mfma(
    const u16* __restrict__ A, int lda,
    const u16* __restrict__ Bt,          // [256 x K]
    const u16* __restrict__ Cadd,        // nullable, [Mpad x 256]
    const float* __restrict__ bias,      // nullable, [256]
    u16* __restrict__ Cout,              // [Mpad x 256]
    int M, int K, int relu) {
    __shared__ u16 Ab[2][GBM * GBK];
    __shared__ u16 Bs[GBN * KMAX];
    const int tid = threadIdx.x;
    const int lane = tid & 63;
    const int wave = tid >> 6;
    const int wm = wave >> 1, wn = wave & 1;
    const int row0 = blockIdx.x * GBM;
    const int col0 = blockIdx.y * GBN;
    const int NOUT = 256;

    {
        const u16* src = Bt + (size_t)col0 * K;
        int chunks = GBN * K / 8;
        for (int c = tid; c < chunks; c += 256) async16(src + c * 8, &Bs[c * 8]);
    }
    stageA(A, lda, row0, 0, Ab[0], tid);
    __syncthreads();

    f32x4 acc[4][2];
    #pragma unroll
    for (int mi = 0; mi < 4; ++mi)
        #pragma unroll
        for (int ni = 0; ni < 2; ++ni) acc[mi][ni] = (f32x4)0.f;

    const int nk = K / GBK;
    const int mb = lane & 15;
    const int kk = (lane >> 4) * 8;
    for (int ks = 0; ks < nk; ++ks) {
        int cur = ks & 1;
        if (ks + 1 < nk) stageA(A, lda, row0, (ks + 1) * GBK, Ab[cur ^ 1], tid);
        bf16x8f a[4], b[2];
        #pragma unroll
        for (int mi = 0; mi < 4; ++mi)
            a[mi] = *(const bf16x8f*)&Ab[cur][(wm * 64 + mi * 16 + mb) * GBK + kk];
        #pragma unroll
        for (int ni = 0; ni < 2; ++ni)
            b[ni] = *(const bf16x8f*)&Bs[(size_t)(wn * 32 + ni * 16 + mb) * K + ks * GBK + kk];
        #pragma unroll
        for (int mi = 0; mi < 4; ++mi)
            #pragma unroll
            for (int ni = 0; ni < 2; ++ni)
                acc[mi][ni] = __builtin_amdgcn_mfma_f32_16x16x32_bf16(
                    a[mi], b[ni], acc[mi][ni], 0, 0, 0);
        __syncthreads();
    }

    #pragma unroll
    for (int mi = 0; mi < 4; ++mi) {
        #pragma unroll
        for (int r = 0; r < 4; ++r) {
            int row = row0 + wm * 64 + mi * 16 + (lane >> 4) * 4 + r;
            if (row < M) {
                #pragma unroll
                for (int ni = 0; ni < 2; ++ni) {
                    int col = col0 + wn * 32 + ni * 16 + (lane & 15);
                    float v = acc[mi][ni][r];
                    if (Cadd) v += u2f(Cadd[(size_t)row * NOUT + col]);
                    if (bias) v += bias[col];
                    if (relu) v = fmaxf(v, 0.f);
                    Cout[(size_t)row * NOUT + col] = f2u(v);
                }
            }
        }
    }
}

// Wt[n*K + k] = bf16(W[k*Nn + n])
__global__ void transpose_cast(const float* __restrict__ W, u16* __restrict__ Wt,
                               int K, int Nn) {
    int idx = blockIdx.x * blockDim.x + threadIdx.x;
    if (idx < K * Nn) {
        int n = idx / K, k = idx % K;
        Wt[idx] = f2u(W[(size_t)k * Nn + n]);
    }
}

// ------------------------------ pool + head --------------------------------

__global__ void pool_kernel(const u16* __restrict__ x, const int* __restrict__ gid,
                            float* __restrict__ pooled, int N, int HID) {
    int t = threadIdx.x;
    int n0 = blockIdx.x * 128;
    int n1 = n0 + 128 < N ? n0 + 128 : N;
    float cur = 0.f;
    int cg = gid[n0];
    for (int n = n0; n < n1; ++n) {
        int g = gid[n];
        if (g != cg) {
            atomicMax((int*)&pooled[(size_t)cg * HID + t], __float_as_int(cur));
            cg = g;
            cur = 0.f;
        }
        float v = u2f(x[(size_t)n * HID + t]);
        cur = cur > v ? cur : v;
    }
    atomicMax((int*)&pooled[(size_t)cg * HID + t], __float_as_int(cur));
}

__global__ void head_kernel(const float* __restrict__ pooled, const float* __restrict__ Wc,
                            const float* __restrict__ bc, float* __restrict__ out,
                            int HID, int C) {
    __shared__ float row[256];
    int g = blockIdx.x;
    int t = threadIdx.x;
    if (t < HID) row[t] = pooled[(size_t)g * HID + t];
    __syncthreads();
    if (t < C) {
        float s = bc[t];
        for (int k = 0; k < HID; ++k) s += row[k] * Wc[(size_t)k * C + t];
        out[(size_t)g * C + t] = s;
    }
}

// ------------------------------- launch ------------------------------------

extern "C" void kernel_launch(void* const* d_in, const int* in_sizes, int n_in,
                              void* d_out, int out_size, void* d_ws, size_t ws_size,
                              hipStream_t stream) {
    const float* h  = (const float*)d_in[0];
    const int* src  = (const int*)d_in[1];
    const int* dst  = (const int*)d_in[2];
    const int* gid  = (const int*)d_in[3];
    const float* W1 = (const float*)d_in[4];
    const float* b1 = (const float*)d_in[5];
    const float* W2 = (const float*)d_in[6];
    const float* b2 = (const float*)d_in[7];
    const float* Wc = (const float*)d_in[8];
    const float* bc = (const float*)d_in[9];
    float* out = (float*)d_out;

    const int N   = in_sizes[3];          // 100000
    const int E   = in_sizes[1];          // 3200000
    const int IN  = in_sizes[0] / N;      // 128
    const int HID = in_sizes[5];          // 256
    const int C   = in_sizes[9];          // 10
    const int G   = out_size / C;         // 64
    const int CAT = 3 * IN;               // 384
    const int Mpad = (N + 127) & ~127;    // 100096 (multiple of GBM)
    const int NB = (N + NPB - 1) / NPB;   // 782 buckets (<= NBMAX)
    const int CS = (E + NC - 1) / NC;     // 25000 edges/chunk

    char* wp = (char*)d_ws;
    auto alloc = [&](size_t bytes) {
        char* p = wp;
        wp += (bytes + 255) & ~(size_t)255;
        return p;
    };
    float* pooled = (float*)alloc((size_t)G * HID * sizeof(float));
    float* normv  = (float*)alloc((size_t)N * sizeof(float));
    float* mv     = (float*)alloc((size_t)N * sizeof(float));
    int* rowptr   = (int*)alloc((size_t)(N + 1) * sizeof(int));
    int* bsum     = (int*)alloc(1024 * sizeof(int));
    int* Omat     = (int*)alloc((size_t)(NB * NC + 1) * sizeof(int));
    int* Hmat     = (int*)alloc((size_t)(NB * NC) * sizeof(int));
    int* colidx   = (int*)alloc((size_t)E * sizeof(int));
    u16* Wt1      = (u16*)alloc((size_t)CAT * HID * sizeof(u16));        // [256 x 384]
    u16* Wt2      = (u16*)alloc((size_t)3 * HID * HID * sizeof(u16));    // 3 x [256 x 256]
    u16* CAT1     = (u16*)alloc((size_t)Mpad * CAT * sizeof(u16));       // [h|Ph|P2h]
    u16* X1       = (u16*)alloc((size_t)Mpad * HID * sizeof(u16));
    u16* B2       = (u16*)alloc((size_t)Mpad * HID * sizeof(u16));
    u16* B1       = CAT1;                              // alias: CAT1 dead after GEMM1
    uint2* Earr   = (uint2*)CAT1;                      // alias: dead before cast writes
    signed char* Q8L2 = (signed char*)(CAT1 + (size_t)Mpad * HID);  // CAT1 tail, layer-2
    signed char* Q8L1 = (signed char*)B2;              // B2 dead during layer 1

    // --- CSR build: counting sort (no global atomics) ---
    const int n2 = NB * NC;               // 100096
    countA_kernel<<<NC, 256, 0, stream>>>(dst, Hmat, E, CS, NB);
    scan1_kernel<<<(n2 + 1023) / 1024, 1024, 0, stream>>>(Hmat, Omat, bsum, n2);
    scan2_kernel<<<1, 1024, 0, stream>>>(bsum, (n2 + 1023) / 1024);
    scan3_kernel<<<(n2 + 255) / 256, 256, 0, stream>>>(Omat, bsum, n2, E);
    scatterC_kernel<<<NC, 256, 0, stream>>>(src, dst, Omat, Earr, E, CS, NB);
    fineD_kernel<<<NB, 256, 0, stream>>>(Earr, Omat, colidx, rowptr, normv, N, E, NB);

    // --- weight transpose + bf16 cast (small) ---
    transpose_cast<<<(CAT * HID + 255) / 256, 256, 0, stream>>>(W1, Wt1, CAT, HID);
    for (int s2 = 0; s2 < 3; ++s2)
        transpose_cast<<<(HID * HID + 255) / 256, 256, 0, stream>>>(
            W2 + (size_t)s2 * HID * HID, Wt2 + (size_t)s2 * HID * HID, HID, HID);

    // --- layer 1: CAT1 = [bf16(h) | P h | P^2 h]; X1 = relu(CAT1@W1+b1) ---
    {
        int ngroups = N * (IN / 4);
        cast_kernel<<<(ngroups + 255) / 256, 256, 0, stream>>>(h, CAT1, ngroups, IN / 4, CAT);
    }
    int pb = (N + 3) / 4;
    quant_f32_128<<<pb, 256, 0, stream>>>(h, normv, Q8L1, mv, N);
    prop_q8_kernel<2><<<pb, 256, 0, stream>>>(Q8L1, mv, CAT1 + IN, CAT,
                                              rowptr, colidx, normv, N);
    quant_bf16_128<<<pb, 256, 0, stream>>>(CAT1 + IN, CAT, normv, Q8L1, mv, N);
    prop_q8_kernel<2><<<pb, 256, 0, stream>>>(Q8L1, mv, CAT1 + 2 * IN, CAT,
                                              rowptr, colidx, normv, N);
    dim3 ggrid(Mpad / GBM, HID / GBN);
    gemm_mfma<<<ggrid, 256, 0, stream>>>(CAT1, CAT, Wt1, nullptr, b1, X1, N, CAT, 1);

    // --- layer 2 (commuted): X2 = relu(X1@W2a + P(X1@W2b + P(X1@W2c)) + b2) ---
    gemm_mfma<<<ggrid, 256, 0, stream>>>(X1, HID, Wt2 + (size_t)2 * HID * HID,
                                         nullptr, nullptr, B1, N, HID, 0);
    quant_bf16_256<<<pb, 256, 0, stream>>>(B1, normv, Q8L2, mv, N);
    prop_q8_kernel<4><<<pb, 256, 0, stream>>>(Q8L2, mv, B2, HID,
                                              rowptr, colidx, normv, N);
    gemm_mfma<<<ggrid, 256, 0, stream>>>(X1, HID, Wt2 + (size_t)HID * HID,
                                         B2, nullptr, B1, N, HID, 0);
    quant_bf16_256<<<pb, 256, 0, stream>>>(B1, normv, Q8L2, mv, N);
    prop_q8_kernel<4><<<pb, 256, 0, stream>>>(Q8L2, mv, B2, HID,
                                              rowptr, colidx, normv, N);
    gemm_mfma<<<ggrid, 256, 0, stream>>>(X1, HID, Wt2, B2, b2, B1, N, HID, 1);

    // --- pool + head ---
    hipMemsetAsync(pooled, 0, (size_t)G * HID * sizeof(float), stream);
    pool_kernel<<<(N + 127) / 128, HID, 0, stream>>>(B1, gid, pooled, N, HID);
    head_kernel<<<G, HID, 0, stream>>>(pooled, Wc, bc, out, HID, C);
}

// Round 9
// 1163.205 us; speedup vs baseline: 1.1919x; 1.0683x over previous
//
#include <hip/hip_runtime.h>
#include <hip/hip_bf16.h>

// ---------------------------------------------------------------------------
// TAGConv (K=2) x2 + segment-max pool + linear head. bf16 intermediates,
// fp32 accumulate, int8 row-quantized gathers for ALL props. Layer-2
// commuted: z2@W2 = X1@W2a + P(X1@W2b + P(X1@W2c)). CSR via counting sort.
// Round 9: GEMM LDS bank-conflict fix (r8: SQ_LDS_BANK_CONFLICT=7.2M/disp,
// MfmaUtil 3.7%). global_load_lds pins LDS chunk c <- lane c, so we XOR-
// swizzle the chunk->data mapping instead: A chunk r*4+s holds k-seg
// s^((r>>1)&3); B chunk n*KC+j holds k-chunk j^(n&7). Both reads then spread
// 16 lanes over 8 bank-groups (2-way = free). GEMM templated on K so K=256
// uses 48KB LDS -> 3 blocks/CU (was 64KB/2).
// ---------------------------------------------------------------------------

typedef unsigned short u16;
typedef unsigned int u32;

__device__ inline float u2f(u16 u) { return __uint_as_float(((u32)u) << 16); }
__device__ inline u16 f2u(float f) {
    __hip_bfloat16 b = __float2bfloat16(f);
    return *reinterpret_cast<u16*>(&b);
}

// ---------------------- CSR build: counting sort ---------------------------
// NPB = 128 nodes per bucket, NC = 128 edge chunks. NB = ceil(N/NPB) <= 784.

constexpr int NPB = 128, NC = 128, NBMAX = 784;

__global__ __launch_bounds__(256) void countA_kernel(
    const int* __restrict__ dst, int* __restrict__ Hmat, int E, int CS, int NB) {
    __shared__ int hist[NBMAX];
    int tid = threadIdx.x;
    for (int b = tid; b < NB; b += 256) hist[b] = 0;
    __syncthreads();
    int base = blockIdx.x * CS;
    int end = base + CS < E ? base + CS : E;
    for (int i = base + tid; i < end; i += 256) {
        int d = __builtin_nontemporal_load(dst + i);
        atomicAdd(&hist[d >> 7], 1);
    }
    __syncthreads();
    for (int b = tid; b < NB; b += 256) Hmat[b * NC + blockIdx.x] = hist[b];
}

__global__ __launch_bounds__(256) void scatterC_kernel(
    const int* __restrict__ src, const int* __restrict__ dst,
    const int* __restrict__ Omat, uint2* __restrict__ Earr,
    int E, int CS, int NB) {
    __shared__ int cur[NBMAX];
    int tid = threadIdx.x;
    int c = blockIdx.x;
    for (int b = tid; b < NB; b += 256) cur[b] = Omat[b * NC + c];
    __syncthreads();
    int base = c * CS;
    int end = base + CS < E ? base + CS : E;
    for (int i = base + tid; i < end; i += 256) {
        int d = __builtin_nontemporal_load(dst + i);
        int s = __builtin_nontemporal_load(src + i);
        int pos = atomicAdd(&cur[d >> 7], 1);
        uint2 e;
        e.x = (u32)s;
        e.y = (u32)(d & (NPB - 1));
        Earr[pos] = e;
    }
}

// One block per bucket: local deg count -> rowptr/normv, then colidx scatter.
__global__ __launch_bounds__(256) void fineD_kernel(
    const uint2* __restrict__ Earr, const int* __restrict__ Omat,
    int* __restrict__ colidx, int* __restrict__ rowptr,
    float* __restrict__ normv, int N, int E, int NB) {
    __shared__ int cnt[NPB];
    __shared__ int scn[NPB];
    __shared__ int cur2[NPB];
    int tid = threadIdx.x;
    int b = blockIdx.x;
    int base = Omat[b * NC];
    int end = Omat[(b + 1) * NC];   // Omat[NB*NC] = E (scan tail)
    if (tid < NPB) cnt[tid] = 0;
    __syncthreads();
    for (int i = base + tid; i < end; i += 256)
        atomicAdd(&cnt[Earr[i].y], 1);
    __syncthreads();
    if (tid < NPB) scn[tid] = cnt[tid];
    __syncthreads();
    for (int off = 1; off < NPB; off <<= 1) {
        int v = (tid < NPB && tid >= off) ? scn[tid - off] : 0;
        __syncthreads();
        if (tid < NPB) scn[tid] += v;
        __syncthreads();
    }
    int node0 = b * NPB;
    if (tid < NPB) {
        int excl = scn[tid] - cnt[tid];
        cur2[tid] = base + excl;
        int node = node0 + tid;
        if (node < N) {
            rowptr[node] = base + excl;
            int d = cnt[tid];
            float fd = d < 1 ? 1.0f : (float)d;
            normv[node] = rsqrtf(fd);
        }
    }
    if (b == 0 && tid == 0) rowptr[N] = E;
    __syncthreads();
    for (int i = base + tid; i < end; i += 256) {
        uint2 e = Earr[i];
        int pos = atomicAdd(&cur2[e.y], 1);
        colidx[pos] = (int)e.x;
    }
}

// Multi-block scan.
__global__ void scan1_kernel(const int* __restrict__ in, int* __restrict__ outp,
                             int* __restrict__ bsum, int n) {
    __shared__ int sd[1024];
    int t = threadIdx.x;
    int i = blockIdx.x * 1024 + t;
    int v = (i < n) ? in[i] : 0;
    sd[t] = v;
    __syncthreads();
    for (int off = 1; off < 1024; off <<= 1) {
        int x = (t >= off) ? sd[t - off] : 0;
        __syncthreads();
        sd[t] += x;
        __syncthreads();
    }
    if (i < n) outp[i] = sd[t] - v;
    if (t == 1023) bsum[blockIdx.x] = sd[t];
}

__global__ void scan2_kernel(int* __restrict__ bsum, int nb) {
    __shared__ int sd[1024];
    int t = threadIdx.x;
    int v = (t < nb) ? bsum[t] : 0;
    sd[t] = v;
    __syncthreads();
    for (int off = 1; off < 1024; off <<= 1) {
        int x = (t >= off) ? sd[t - off] : 0;
        __syncthreads();
        sd[t] += x;
        __syncthreads();
    }
    if (t < nb) bsum[t] = sd[t] - v;
}

__global__ void scan3_kernel(int* __restrict__ outp, const int* __restrict__ bsum,
                             int n, int E) {
    int i = blockIdx.x * blockDim.x + threadIdx.x;
    if (i < n) outp[i] += bsum[i >> 10];
    if (i == 0) outp[n] = E;
}

// ------------------------------ cast h -------------------------------------

struct alignas(4) U2 { u16 v[2]; };
struct alignas(8) U4 { u16 v[4]; };

__global__ void cast_kernel(const float* __restrict__ h, u16* __restrict__ cat,
                            int ngroups, int in4, int ldcat) {
    int i = blockIdx.x * blockDim.x + threadIdx.x;
    if (i < ngroups) {
        int r = i / in4, c4 = i % in4;
        float4 f = *(const float4*)(h + (size_t)i * 4);
        U4 o;
        o.v[0] = f2u(f.x); o.v[1] = f2u(f.y); o.v[2] = f2u(f.z); o.v[3] = f2u(f.w);
        *(U4*)(cat + (size_t)r * ldcat + c4 * 4) = o;
    }
}

// --------------------------- int8 quantization -----------------------------

__global__ __launch_bounds__(256) void quant_f32_128(
    const float* __restrict__ x, const float* __restrict__ normv,
    signed char* __restrict__ q, float* __restrict__ m, int N) {
    int row = blockIdx.x * 4 + (threadIdx.x >> 6);
    if (row >= N) return;
    int lane = threadIdx.x & 63;
    float2 f = *(const float2*)(x + (size_t)row * 128 + lane * 2);
    float mx = fmaxf(fabsf(f.x), fabsf(f.y));
    #pragma unroll
    for (int off = 32; off > 0; off >>= 1)
        mx = fmaxf(mx, __shfl_xor(mx, off, 64));
    float inv = mx > 0.f ? 127.f / mx : 0.f;
    char2 o;
    o.x = (signed char)(int)rintf(f.x * inv);
    o.y = (signed char)(int)rintf(f.y * inv);
    *(char2*)(q + (size_t)row * 128 + lane * 2) = o;
    if (lane == 0) m[row] = normv[row] * (mx * (1.f / 127.f));
}

__global__ __launch_bounds__(256) void quant_bf16_128(
    const u16* __restrict__ x, int ldx, const float* __restrict__ normv,
    signed char* __restrict__ q, float* __restrict__ m, int N) {
    int row = blockIdx.x * 4 + (threadIdx.x >> 6);
    if (row >= N) return;
    int lane = threadIdx.x & 63;
    U2 v = *(const U2*)(x + (size_t)row * ldx + lane * 2);
    float f0 = u2f(v.v[0]), f1 = u2f(v.v[1]);
    float mx = fmaxf(fabsf(f0), fabsf(f1));
    #pragma unroll
    for (int off = 32; off > 0; off >>= 1)
        mx = fmaxf(mx, __shfl_xor(mx, off, 64));
    float inv = mx > 0.f ? 127.f / mx : 0.f;
    char2 o;
    o.x = (signed char)(int)rintf(f0 * inv);
    o.y = (signed char)(int)rintf(f1 * inv);
    *(char2*)(q + (size_t)row * 128 + lane * 2) = o;
    if (lane == 0) m[row] = normv[row] * (mx * (1.f / 127.f));
}

__global__ __launch_bounds__(256) void quant_bf16_256(
    const u16* __restrict__ x, const float* __restrict__ normv,
    signed char* __restrict__ q, float* __restrict__ m, int N) {
    int row = blockIdx.x * 4 + (threadIdx.x >> 6);
    if (row >= N) return;
    int lane = threadIdx.x & 63;
    U4 v = *(const U4*)(x + (size_t)row * 256 + lane * 4);
    float f[4];
    #pragma unroll
    for (int i = 0; i < 4; ++i) f[i] = u2f(v.v[i]);
    float mx = fmaxf(fmaxf(fabsf(f[0]), fabsf(f[1])),
                     fmaxf(fabsf(f[2]), fabsf(f[3])));
    #pragma unroll
    for (int off = 32; off > 0; off >>= 1)
        mx = fmaxf(mx, __shfl_xor(mx, off, 64));
    float inv = mx > 0.f ? 127.f / mx : 0.f;
    char4 o;
    o.x = (signed char)(int)rintf(f[0] * inv);
    o.y = (signed char)(int)rintf(f[1] * inv);
    o.z = (signed char)(int)rintf(f[2] * inv);
    o.w = (signed char)(int)rintf(f[3] * inv);
    *(char4*)(q + (size_t)row * 256 + lane * 4) = o;
    if (lane == 0) m[row] = normv[row] * (mx * (1.f / 127.f));
}

// ------------------------- int8 row-quantized prop -------------------------

template <int FPL>
__global__ __launch_bounds__(256) void prop_q8_kernel(
    const signed char* __restrict__ qin, const float* __restrict__ m,
    u16* __restrict__ out, int ldout,
    const int* __restrict__ rowptr, const int* __restrict__ colidx,
    const float* __restrict__ normv, int N) {
    const int D = 64 * FPL;
    int node = blockIdx.x * 4 + (threadIdx.x >> 6);
    if (node >= N) return;
    int lane = threadIdx.x & 63;
    const signed char* ip = qin + lane * FPL;
    int s = rowptr[node], e = rowptr[node + 1];
    float acc[FPL];
    #pragma unroll
    for (int q = 0; q < FPL; ++q) acc[q] = 0.f;
    int p = s;
    for (; p + 8 <= e; p += 8) {
        int c[8];
        #pragma unroll
        for (int j = 0; j < 8; ++j) c[j] = colidx[p + j];
        int w[8];
        #pragma unroll
        for (int j = 0; j < 8; ++j) {
            if (FPL == 4) w[j] = *(const int*)(ip + (size_t)c[j] * D);
            else          w[j] = *(const unsigned short*)(ip + (size_t)c[j] * D);
        }
        float nm[8];
        #pragma unroll
        for (int j = 0; j < 8; ++j) nm[j] = m[c[j]];
        #pragma unroll
        for (int j = 0; j < 8; ++j) {
            acc[0] += nm[j] * (float)(signed char)(w[j]);
            acc[1] += nm[j] * (float)(signed char)(w[j] >> 8);
            if (FPL == 4) {
                acc[2] += nm[j] * (float)(signed char)(w[j] >> 16);
                acc[3] += nm[j] * (float)(w[j] >> 24);
            }
        }
    }
    for (; p < e; ++p) {
        int c = colidx[p];
        int w;
        if (FPL == 4) w = *(const int*)(ip + (size_t)c * D);
        else          w = *(const unsigned short*)(ip + (size_t)c * D);
        float nm = m[c];
        acc[0] += nm * (float)(signed char)(w);
        acc[1] += nm * (float)(signed char)(w >> 8);
        if (FPL == 4) {
            acc[2] += nm * (float)(signed char)(w >> 16);
            acc[3] += nm * (float)(w >> 24);
        }
    }
    float nn = normv[node];
    if (FPL == 4) {
        U4 o;
        #pragma unroll
        for (int q = 0; q < 4; ++q) o.v[q] = f2u(nn * acc[q]);
        *(U4*)(out + (size_t)node * ldout + lane * 4) = o;
    } else {
        U2 o;
        o.v[0] = f2u(nn * acc[0]);
        o.v[1] = f2u(nn * acc[1]);
        *(U2*)(out + (size_t)node * ldout + lane * 2) = o;
    }
}

// ------------------------------- MFMA GEMM ---------------------------------
// Cout[M x 256] = [relu]( A(bf16,[Mpad x lda]) @ Bt^T [+Cadd] [+bias] ) -> bf16
// Bt is [256 x KK] bf16 row-major. Tile 128x64, BK=32, 4 waves (2x2).
// XOR-swizzled LDS layouts (see header comment): A chunk r*4+s holds k-seg
// s^((r>>1)&3); B chunk n*KC+j holds k-chunk j^(n&7). 16B chunks.

typedef __attribute__((ext_vector_type(8))) short bf16x8f;
typedef __attribute__((ext_vector_type(4))) float f32x4;

__device__ inline void async16(const void* g, void* l) {
    __builtin_amdgcn_global_load_lds(
        (__attribute__((address_space(1))) void*)(g),
        (__attribute__((address_space(3))) void*)(l), 16, 0, 0);
}

constexpr int GBM = 128, GBN = 64, GBK = 32;

__device__ inline void stageA_sw(const u16* __restrict__ A, int lda, int row0,
                                 int k0, u16* dst, int tid) {
    // LDS chunk c holds (row = c>>2, k-seg = (c&3) ^ ((row>>1)&3)).
    #pragma unroll
    for (int i = 0; i < 2; ++i) {
        int c = tid + i * 256;
        int row = c >> 2;
        int seg = (c & 3) ^ ((row >> 1) & 3);
        async16(A + (size_t)(row0 + row) * lda + k0 + seg * 8, dst + c * 8);
    }
}

template <int KK>
__global__ __launch_bounds__(256) void gemm_mfma(
    const u16* __restrict__ A, int lda,
    const u16* __restrict__ Bt,          // [256 x KK]
    const u16* __restrict__ Cadd,        // nullable, [Mpad x 256]
    const float* __restrict__ bias,      // nullable, [256]
    u16* __restrict__ Cout,              // [Mpad x 256]
    int M, int relu) {
    constexpr int KC = KK / 8;           // 16B chunks per B row
    __shared__ u16 Ab[2][GBM * GBK];
    __shared__ u16 Bs[GBN * KK];
    const int tid = threadIdx.x;
    const int lane = tid & 63;
    const int wave = tid >> 6;
    const int wm = wave >> 1, wn = wave & 1;
    const int row0 = blockIdx.x * GBM;
    const int col0 = blockIdx.y * GBN;
    const int NOUT = 256;

    // stage B panel, swizzled: LDS chunk cb holds (n = cb/KC, j = (cb%KC)^(n&7))
    {
        const u16* srcB = Bt + (size_t)col0 * KK;
        #pragma unroll
        for (int i = 0; i < GBN * KC / 256; ++i) {
            int cb = tid + i * 256;
            int n = cb / KC;
            int j = (cb % KC) ^ (n & 7);
            async16(srcB + (size_t)n * KK + j * 8, &Bs[cb * 8]);
        }
    }
    stageA_sw(A, lda, row0, 0, Ab[0], tid);
    __syncthreads();

    f32x4 acc[4][2];
    #pragma unroll
    for (int mi = 0; mi < 4; ++mi)
        #pragma unroll
        for (int ni = 0; ni < 2; ++ni) acc[mi][ni] = (f32x4)0.f;

    constexpr int nk = KK / GBK;
    const int mb = lane & 15;
    const int seg = lane >> 4;           // k-seg within 32-wide tile (0..3)
    for (int ks = 0; ks < nk; ++ks) {
        int cur = ks & 1;
        if (ks + 1 < nk) stageA_sw(A, lda, row0, (ks + 1) * GBK, Ab[cur ^ 1], tid);
        bf16x8f a[4], b[2];
        #pragma unroll
        for (int mi = 0; mi < 4; ++mi) {
            int r = wm * 64 + mi * 16 + mb;
            int ca = r * 4 + (seg ^ ((r >> 1) & 3));
            a[mi] = *(const bf16x8f*)&Ab[cur][ca * 8];
        }
        #pragma unroll
        for (int ni = 0; ni < 2; ++ni) {
            int n = wn * 32 + ni * 16 + mb;
            int jk = ks * 4 + seg;
            int cb = n * KC + (jk ^ (n & 7));
            b[ni] = *(const bf16x8f*)&Bs[cb * 8];
        }
        #pragma unroll
        for (int mi = 0; mi < 4; ++mi)
            #pragma unroll
            for (int ni = 0; ni < 2; ++ni)
                acc[mi][ni] = __builtin_amdgcn_mfma_f32_16x16x32_bf16(
                    a[mi], b[ni], acc[mi][ni], 0, 0, 0);
        __syncthreads();
    }

    // epilogue: C/D layout col = lane&15, row = (lane>>4)*4 + r
    #pragma unroll
    for (int mi = 0; mi < 4; ++mi) {
        #pragma unroll
        for (int r = 0; r < 4; ++r) {
            int row = row0 + wm * 64 + mi * 16 + (lane >> 4) * 4 + r;
            if (row < M) {
                #pragma unroll
                for (int ni = 0; ni < 2; ++ni) {
                    int col = col0 + wn * 32 + ni * 16 + (lane & 15);
                    float v = acc[mi][ni][r];
                    if (Cadd) v += u2f(Cadd[(size_t)row * NOUT + col]);
                    if (bias) v += bias[col];
                    if (relu) v = fmaxf(v, 0.f);
                    Cout[(size_t)row * NOUT + col] = f2u(v);
                }
            }
        }
    }
}

// Wt[n*K + k] = bf16(W[k*Nn + n])
__global__ void transpose_cast(const float* __restrict__ W, u16* __restrict__ Wt,
                               int K, int Nn) {
    int idx = blockIdx.x * blockDim.x + threadIdx.x;
    if (idx < K * Nn) {
        int n = idx / K, k = idx % K;
        Wt[idx] = f2u(W[(size_t)k * Nn + n]);
    }
}

// ------------------------------ pool + head --------------------------------

__global__ void pool_kernel(const u16* __restrict__ x, const int* __restrict__ gid,
                            float* __restrict__ pooled, int N, int HID) {
    int t = threadIdx.x;
    int n0 = blockIdx.x * 128;
    int n1 = n0 + 128 < N ? n0 + 128 : N;
    float cur = 0.f;
    int cg = gid[n0];
    for (int n = n0; n < n1; ++n) {
        int g = gid[n];
        if (g != cg) {
            atomicMax((int*)&pooled[(size_t)cg * HID + t], __float_as_int(cur));
            cg = g;
            cur = 0.f;
        }
        float v = u2f(x[(size_t)n * HID + t]);
        cur = cur > v ? cur : v;
    }
    atomicMax((int*)&pooled[(size_t)cg * HID + t], __float_as_int(cur));
}

__global__ void head_kernel(const float* __restrict__ pooled, const float* __restrict__ Wc,
                            const float* __restrict__ bc, float* __restrict__ out,
                            int HID, int C) {
    __shared__ float row[256];
    int g = blockIdx.x;
    int t = threadIdx.x;
    if (t < HID) row[t] = pooled[(size_t)g * HID + t];
    __syncthreads();
    if (t < C) {
        float s = bc[t];
        for (int k = 0; k < HID; ++k) s += row[k] * Wc[(size_t)k * C + t];
        out[(size_t)g * C + t] = s;
    }
}

// ------------------------------- launch ------------------------------------

extern "C" void kernel_launch(void* const* d_in, const int* in_sizes, int n_in,
                              void* d_out, int out_size, void* d_ws, size_t ws_size,
                              hipStream_t stream) {
    const float* h  = (const float*)d_in[0];
    const int* src  = (const int*)d_in[1];
    const int* dst  = (const int*)d_in[2];
    const int* gid  = (const int*)d_in[3];
    const float* W1 = (const float*)d_in[4];
    const float* b1 = (const float*)d_in[5];
    const float* W2 = (const float*)d_in[6];
    const float* b2 = (const float*)d_in[7];
    const float* Wc = (const float*)d_in[8];
    const float* bc = (const float*)d_in[9];
    float* out = (float*)d_out;

    const int N   = in_sizes[3];          // 100000
    const int E   = in_sizes[1];          // 3200000
    const int IN  = in_sizes[0] / N;      // 128
    const int HID = in_sizes[5];          // 256
    const int C   = in_sizes[9];          // 10
    const int G   = out_size / C;         // 64
    const int CAT = 3 * IN;               // 384
    const int Mpad = (N + 127) & ~127;    // 100096 (multiple of GBM)
    const int NB = (N + NPB - 1) / NPB;   // 782 buckets (<= NBMAX)
    const int CS = (E + NC - 1) / NC;     // 25000 edges/chunk

    char* wp = (char*)d_ws;
    auto alloc = [&](size_t bytes) {
        char* p = wp;
        wp += (bytes + 255) & ~(size_t)255;
        return p;
    };
    float* pooled = (float*)alloc((size_t)G * HID * sizeof(float));
    float* normv  = (float*)alloc((size_t)N * sizeof(float));
    float* mv     = (float*)alloc((size_t)N * sizeof(float));
    int* rowptr   = (int*)alloc((size_t)(N + 1) * sizeof(int));
    int* bsum     = (int*)alloc(1024 * sizeof(int));
    int* Omat     = (int*)alloc((size_t)(NB * NC + 1) * sizeof(int));
    int* Hmat     = (int*)alloc((size_t)(NB * NC) * sizeof(int));
    int* colidx   = (int*)alloc((size_t)E * sizeof(int));
    u16* Wt1      = (u16*)alloc((size_t)CAT * HID * sizeof(u16));        // [256 x 384]
    u16* Wt2      = (u16*)alloc((size_t)3 * HID * HID * sizeof(u16));    // 3 x [256 x 256]
    u16* CAT1     = (u16*)alloc((size_t)Mpad * CAT * sizeof(u16));       // [h|Ph|P2h]
    u16* X1       = (u16*)alloc((size_t)Mpad * HID * sizeof(u16));
    u16* B2       = (u16*)alloc((size_t)Mpad * HID * sizeof(u16));
    u16* B1       = CAT1;                              // alias: CAT1 dead after GEMM1
    uint2* Earr   = (uint2*)CAT1;                      // alias: dead before cast writes
    signed char* Q8L2 = (signed char*)(CAT1 + (size_t)Mpad * HID);  // CAT1 tail, layer-2
    signed char* Q8L1 = (signed char*)B2;              // B2 dead during layer 1

    // --- CSR build: counting sort (no global atomics) ---
    const int n2 = NB * NC;               // 100096
    countA_kernel<<<NC, 256, 0, stream>>>(dst, Hmat, E, CS, NB);
    scan1_kernel<<<(n2 + 1023) / 1024, 1024, 0, stream>>>(Hmat, Omat, bsum, n2);
    scan2_kernel<<<1, 1024, 0, stream>>>(bsum, (n2 + 1023) / 1024);
    scan3_kernel<<<(n2 + 255) / 256, 256, 0, stream>>>(Omat, bsum, n2, E);
    scatterC_kernel<<<NC, 256, 0, stream>>>(src, dst, Omat, Earr, E, CS, NB);
    fineD_kernel<<<NB, 256, 0, stream>>>(Earr, Omat, colidx, rowptr, normv, N, E, NB);

    // --- weight transpose + bf16 cast (small) ---
    transpose_cast<<<(CAT * HID + 255) / 256, 256, 0, stream>>>(W1, Wt1, CAT, HID);
    for (int s2 = 0; s2 < 3; ++s2)
        transpose_cast<<<(HID * HID + 255) / 256, 256, 0, stream>>>(
            W2 + (size_t)s2 * HID * HID, Wt2 + (size_t)s2 * HID * HID, HID, HID);

    // --- layer 1: CAT1 = [bf16(h) | P h | P^2 h]; X1 = relu(CAT1@W1+b1) ---
    {
        int ngroups = N * (IN / 4);
        cast_kernel<<<(ngroups + 255) / 256, 256, 0, stream>>>(h, CAT1, ngroups, IN / 4, CAT);
    }
    int pb = (N + 3) / 4;
    quant_f32_128<<<pb, 256, 0, stream>>>(h, normv, Q8L1, mv, N);
    prop_q8_kernel<2><<<pb, 256, 0, stream>>>(Q8L1, mv, CAT1 + IN, CAT,
                                              rowptr, colidx, normv, N);
    quant_bf16_128<<<pb, 256, 0, stream>>>(CAT1 + IN, CAT, normv, Q8L1, mv, N);
    prop_q8_kernel<2><<<pb, 256, 0, stream>>>(Q8L1, mv, CAT1 + 2 * IN, CAT,
                                              rowptr, colidx, normv, N);
    dim3 ggrid(Mpad / GBM, HID / GBN);
    gemm_mfma<384><<<ggrid, 256, 0, stream>>>(CAT1, CAT, Wt1, nullptr, b1, X1, N, 1);

    // --- layer 2 (commuted): X2 = relu(X1@W2a + P(X1@W2b + P(X1@W2c)) + b2) ---
    gemm_mfma<256><<<ggrid, 256, 0, stream>>>(X1, HID, Wt2 + (size_t)2 * HID * HID,
                                              nullptr, nullptr, B1, N, 0);
    quant_bf16_256<<<pb, 256, 0, stream>>>(B1, normv, Q8L2, mv, N);
    prop_q8_kernel<4><<<pb, 256, 0, stream>>>(Q8L2, mv, B2, HID,
                                              rowptr, colidx, normv, N);
    gemm_mfma<256><<<ggrid, 256, 0, stream>>>(X1, HID, Wt2 + (size_t)HID * HID,
                                              B2, nullptr, B1, N, 0);
    quant_bf16_256<<<pb, 256, 0, stream>>>(B1, normv, Q8L2, mv, N);
    prop_q8_kernel<4><<<pb, 256, 0, stream>>>(Q8L2, mv, B2, HID,
                                              rowptr, colidx, normv, N);
    gemm_mfma<256><<<ggrid, 256, 0, stream>>>(X1, HID, Wt2, B2, b2, B1, N, 1);

    // --- pool + head ---
    hipMemsetAsync(pooled, 0, (size_t)G * HID * sizeof(float), stream);
    pool_kernel<<<(N + 127) / 128, HID, 0, stream>>>(B1, gid, pooled, N, HID);
    head_kernel<<<G, HID, 0, stream>>>(pooled, Wc, bc, out, HID, C);
}